// Round 7
// baseline (475.153 us; speedup 1.0000x reference)
//
#include <hip/hip_runtime.h>
#include <hip/hip_bf16.h>
#include <stdint.h>

#define N_TOK 4096
#define DIM   1024
#define NE    8
#define HID   4096
#define OUTD  1024
#define TOPK  2
#define SLOTS (N_TOK*TOPK)
#define SLOTS_PAD (SLOTS+256)

typedef __bf16 bf16_t;
typedef __attribute__((ext_vector_type(8))) __bf16 bf16x8;
typedef __attribute__((ext_vector_type(4))) __bf16 bf16x4;
typedef __attribute__((ext_vector_type(4))) float  f32x4;

// ---------------- fused gating (fp64 logits, top-2, softmax) + x -> bf16 cast ----------------
__global__ void k_gatecast(const float* __restrict__ x, const float* __restrict__ wg,
                           bf16_t* __restrict__ xb,
                           int* __restrict__ tki, float* __restrict__ tkg,
                           int* __restrict__ counts) {
    int n = blockIdx.x;
    int lane = threadIdx.x;            // 64 threads = 1 wave
    const float* xr = x + (size_t)n * DIM;
    double acc[NE];
#pragma unroll
    for (int e = 0; e < NE; ++e) acc[e] = 0.0;
#pragma unroll
    for (int i = 0; i < 4; ++i) {
        int d0 = i * 256 + lane * 4;
        float4 v = *(const float4*)&xr[d0];
        bf16x4 o;
        o[0] = (__bf16)v.x; o[1] = (__bf16)v.y; o[2] = (__bf16)v.z; o[3] = (__bf16)v.w;
        *(bf16x4*)&xb[(size_t)n * DIM + d0] = o;
        const float* wr = wg + (size_t)d0 * NE;
#pragma unroll
        for (int j = 0; j < 4; ++j) {
            double xv = (double)((&v.x)[j]);
#pragma unroll
            for (int e = 0; e < NE; ++e) acc[e] += xv * (double)wr[j * NE + e];
        }
    }
#pragma unroll
    for (int e = 0; e < NE; ++e)
        for (int off = 32; off > 0; off >>= 1) acc[e] += __shfl_xor(acc[e], off);
    if (lane == 0) {
        int i0 = 0; double v0 = acc[0];
#pragma unroll
        for (int e = 1; e < NE; ++e) if (acc[e] > v0) { v0 = acc[e]; i0 = e; }
        int i1 = -1; double v1 = -1e300;
#pragma unroll
        for (int e = 0; e < NE; ++e) if (e != i0 && acc[e] > v1) { v1 = acc[e]; i1 = e; }
        double e1 = exp(v1 - v0);
        double s = 1.0 + e1;
        tki[n*2]   = i0;  tki[n*2+1] = i1;
        tkg[n*2]   = (float)(1.0 / s);
        tkg[n*2+1] = (float)(e1 / s);
        atomicAdd(&counts[i0], 1);
        atomicAdd(&counts[i1], 1);
    }
}

// ---------------- importance: deterministic per-expert reduction ----------------
__global__ void k_importance(const int* __restrict__ tki, const float* __restrict__ tkg,
                             float* __restrict__ imp) {
    int e = blockIdx.x, t = threadIdx.x;
    __shared__ float red[256];
    float s = 0.f;
    for (int i = t; i < SLOTS; i += 256) s += (tki[i] == e) ? tkg[i] : 0.f;
    red[t] = s; __syncthreads();
    for (int off = 128; off > 0; off >>= 1) {
        if (t < off) red[t] += red[t + off];
        __syncthreads();
    }
    if (t == 0) imp[e] = red[0];
}

// ---------------- aux loss + prefix-sum bases ----------------
__global__ void k_finalize(const float* __restrict__ imp, const int* __restrict__ counts,
                           int* __restrict__ bases, float* __restrict__ aux_out) {
    if (threadIdx.x == 0 && blockIdx.x == 0) {
        float m = 0.f;
        for (int e = 0; e < NE; ++e) m += imp[e];
        m /= (float)NE;
        float var = 0.f;
        for (int e = 0; e < NE; ++e) { float d = imp[e] - m; var += d * d; }
        var /= (float)NE;
        aux_out[0] = 0.01f * var / (m * m + 1e-10f);
        int b = 0;
        for (int e = 0; e < NE; ++e) { bases[e] = b; b += counts[e]; }
    }
}

// ---------------- build per-expert token lists + inverse slot map ----------------
__global__ void k_build(const int* __restrict__ tki,
                        const int* __restrict__ bases, int* __restrict__ cursor,
                        int* __restrict__ tok_ids, int* __restrict__ slotmap) {
    int i = blockIdx.x * 256 + threadIdx.x;
    if (i < SLOTS) {
        int e = tki[i];
        int p = atomicAdd(&cursor[e], 1);
        int s = bases[e] + p;
        tok_ids[s] = i >> 1;
        slotmap[i] = s;
    }
}

// ---------------- W [E][R][C] fp32 -> Wt [E][C][R] bf16, 64x64 tiles ----------------
__global__ void k_transpose(const float* __restrict__ src, bf16_t* __restrict__ dst,
                            int R, int C) {
    __shared__ float tile[64][65];
    const size_t slab = (size_t)R * C;
    const float* s = src + slab * blockIdx.z;
    bf16_t*      d = dst + slab * blockIdx.z;
    int c0 = blockIdx.x * 64, r0 = blockIdx.y * 64;
    int tx = threadIdx.x & 15;
    int ty = threadIdx.x >> 4;
#pragma unroll
    for (int p = 0; p < 4; ++p) {
        int rr = p * 16 + ty;
        float4 v = *(const float4*)&s[(size_t)(r0 + rr) * C + c0 + tx * 4];
        tile[rr][tx*4+0] = v.x; tile[rr][tx*4+1] = v.y;
        tile[rr][tx*4+2] = v.z; tile[rr][tx*4+3] = v.w;
    }
    __syncthreads();
#pragma unroll
    for (int p = 0; p < 4; ++p) {
        int rr = p * 16 + ty;          // dst row (= source column)
        int cc = tx * 4;               // dst col (= source row)
        bf16x4 o;
        o[0] = (__bf16)tile[cc+0][rr]; o[1] = (__bf16)tile[cc+1][rr];
        o[2] = (__bf16)tile[cc+2][rr]; o[3] = (__bf16)tile[cc+3][rr];
        *(bf16x4*)&d[(size_t)(c0 + rr) * R + r0 + cc] = o;
    }
}

// ---------------- grouped GEMM, 256x256 tile, BK=32, 8 waves, counted-vmcnt depth-2 ----------------
// 4 LDS buffers (32 KiB each). Iter kt: vmcnt(4) [kt+1 stays in flight] -> s_barrier ->
// issue kt+2 (4 GLL/wave) -> {4+4 ds_read, lgkm0, 16 MFMA} x2 phases. vmcnt never drains
// in steady state (T4); loads lead consumption by 2 K-tiles (~1us). Buf (kt+2)&3 was last
// read at iter kt-2 (2 barriers ago) -> race-free. Swizzle (64B rows): chunk ^= (row&3)^((row>>2)&3),
// applied both-sides (GLL source pre-permute + read-side XOR).
// MODE 0: hbuf[slot] = relu(x_gather @ W1t^T + b1)
// MODE 1 (KSPLIT=2): Y[kslot][slot] = h @ W2t^T (+b2 on kslot 0), partials combined later.
template <int MODE, int KSPLIT>
__global__ __launch_bounds__(512, 2)
void k_gemm(const bf16_t* __restrict__ A,    // MODE0: xb [N][DIM]; MODE1: hbuf [SLOTS_PAD][HID]
            const bf16_t* __restrict__ Bt,   // MODE0: w1t [E][HID][DIM]; MODE1: w2t [E][OUTD][HID]
            const float* __restrict__ bias,  // MODE0: b1 [E][HID]; MODE1: b2 [E][OUTD]
            const int* __restrict__ tok_ids,
            const int* __restrict__ bases,
            const int* __restrict__ counts,
            bf16_t* __restrict__ Y) {
    constexpr int KD   = (MODE == 0) ? DIM : HID;
    constexpr int ND   = (MODE == 0) ? HID : OUTD;
    constexpr int NP   = ND / 256;
    constexpr int KLEN = KD / KSPLIT;
    constexpr int KT   = KLEN / 32;
    constexpr int BUFE = 16384;     // elems per buffer: A 8192 + B 8192 (32 KiB)
    constexpr int ZB   = 4;

    const int e     = blockIdx.x & 7;       // expert pinned to XCD
    int rest        = blockIdx.x >> 3;
    const int panel = rest % NP;  rest /= NP;
    const int z     = rest % ZB;
    const int kslot = rest / ZB;            // [0, KSPLIT)
    const int ne = counts[e];
    const int b0 = bases[e];
    const int n0 = panel * 256;
    const int koff = kslot * KLEN;

    // split-K partials go to separate slabs (FIX for R6: kslot offset was missing)
    bf16_t* __restrict__ Yw = Y + (size_t)kslot * SLOTS_PAD * ND;

    extern __shared__ bf16_t lds[];         // 4 * BUFE elems = 128 KiB

    const int t = threadIdx.x, w = t >> 6, L = t & 63;
    const int wm = w >> 2, wn = w & 3;      // 2 x 4 wave grid; per-wave out 128x64
    const int lr = L & 15, lq = L >> 4;

    // staging: wave w, instr s covers rows w*32+s*16 .. +15; lane L: row-local L>>2, chunk L&3
    const int Lrow = L >> 2;
    const int srcc = (((L & 3) ^ (Lrow & 3) ^ ((L >> 4) & 3)) << 3);  // pre-swizzled col (elems)
    const int dstA0 = w * 1024;             // + s*512 ; B adds 8192

    // fragment read offsets (elems, within buffer)
    const int pch = ((lq ^ (lr & 3) ^ (lr >> 2)) << 3);
    int offA[8], offB[4];
#pragma unroll
    for (int i = 0; i < 8; ++i) offA[i] = (wm * 128 + i * 16 + lr) * 32 + pch;
#pragma unroll
    for (int j = 0; j < 4; ++j) offB[j] = 8192 + (wn * 64 + j * 16 + lr) * 32 + pch;

    // B stage pointers (rows fixed per block)
    const bf16_t* bptr[2];
#pragma unroll
    for (int s = 0; s < 2; ++s)
        bptr[s] = Bt + ((size_t)e * ND + n0 + w * 32 + s * 16 + Lrow) * KD + koff + srcc;

#define GLL(srcp, dste) __builtin_amdgcn_global_load_lds( \
        (const __attribute__((address_space(1))) uint32_t*)(srcp), \
        (__attribute__((address_space(3))) uint32_t*)(lds + (dste)), 16, 0, 0)

    for (int y = z; y * 256 < ne; y += ZB) {
        const int m0 = y * 256;

        const bf16_t* aptr[2];
#pragma unroll
        for (int s = 0; s < 2; ++s) {
            int mm = m0 + w * 32 + s * 16 + Lrow;
            int rr = (mm < ne) ? mm : (ne - 1);
            if (MODE == 0) {
                int tok = tok_ids[b0 + rr];
                aptr[s] = A + (size_t)tok * KD + koff + srcc;
            } else {
                aptr[s] = A + (size_t)(b0 + rr) * KD + koff + srcc;
            }
        }

        f32x4 acc[8][4];
#pragma unroll
        for (int i = 0; i < 8; ++i)
#pragma unroll
            for (int j = 0; j < 4; ++j) acc[i][j] = (f32x4){0.f, 0.f, 0.f, 0.f};

        // prologue: stage K-tiles 0 and 1 (depth 2; 8 GLL outstanding)
#pragma unroll
        for (int pt = 0; pt < 2; ++pt) {
#pragma unroll
            for (int s = 0; s < 2; ++s) {
                GLL(aptr[s] + pt * 32, pt * BUFE + dstA0 + s * 512);
                GLL(bptr[s] + pt * 32, pt * BUFE + 8192 + dstA0 + s * 512);
            }
        }

        for (int kt = 0; kt < KT; ++kt) {
            // my tile-kt loads landed; kt+1's stay in flight (no drain in steady state)
            if (kt < KT - 1) asm volatile("s_waitcnt vmcnt(4)" ::: "memory");
            else             asm volatile("s_waitcnt vmcnt(0)" ::: "memory");
            __builtin_amdgcn_s_barrier();
            __builtin_amdgcn_sched_barrier(0);

            // issue kt+2 into buf (kt+2)&3 (last read at iter kt-2 -> safe)
            if (kt + 2 < KT) {
                const int nb = (kt + 2) & 3;
#pragma unroll
                for (int s = 0; s < 2; ++s) {
                    GLL(aptr[s] + (kt + 2) * 32, nb * BUFE + dstA0 + s * 512);
                    GLL(bptr[s] + (kt + 2) * 32, nb * BUFE + 8192 + dstA0 + s * 512);
                }
            }

            const bf16_t* bb = lds + (kt & 3) * BUFE;

            // phase 1: fb all + fa 0..3, MFMA upper half
            bf16x8 fb[4], fa[4];
#pragma unroll
            for (int j = 0; j < 4; ++j) fb[j] = *(const bf16x8*)(bb + offB[j]);
#pragma unroll
            for (int i = 0; i < 4; ++i) fa[i] = *(const bf16x8*)(bb + offA[i]);
            asm volatile("s_waitcnt lgkmcnt(0)" ::: "memory");
            __builtin_amdgcn_sched_barrier(0);
            __builtin_amdgcn_s_setprio(1);
#pragma unroll
            for (int i = 0; i < 4; ++i)
#pragma unroll
                for (int j = 0; j < 4; ++j)
                    acc[i][j] = __builtin_amdgcn_mfma_f32_16x16x32_bf16(fb[j], fa[i], acc[i][j], 0, 0, 0);
            __builtin_amdgcn_s_setprio(0);

            // phase 2: fa 4..7, MFMA lower half
            bf16x8 fa2[4];
#pragma unroll
            for (int i = 0; i < 4; ++i) fa2[i] = *(const bf16x8*)(bb + offA[4 + i]);
            asm volatile("s_waitcnt lgkmcnt(0)" ::: "memory");
            __builtin_amdgcn_sched_barrier(0);
            __builtin_amdgcn_s_setprio(1);
#pragma unroll
            for (int i = 0; i < 4; ++i)
#pragma unroll
                for (int j = 0; j < 4; ++j)
                    acc[4 + i][j] = __builtin_amdgcn_mfma_f32_16x16x32_bf16(fb[j], fa2[i], acc[4 + i][j], 0, 0, 0);
            __builtin_amdgcn_s_setprio(0);
        }

        // ---------------- epilogue: bf16 store ----------------
#pragma unroll
        for (int a = 0; a < 8; ++a) {
            int ml = wm * 128 + a * 16 + lr;
            int gm = m0 + ml;
            if (gm < ne) {
#pragma unroll
                for (int j = 0; j < 4; ++j) {
                    int gn = n0 + wn * 64 + j * 16 + lq * 4;
                    bf16x4 hv;
                    f32x4 bv = *(const f32x4*)&bias[(size_t)e * ND + gn];
#pragma unroll
                    for (int r2 = 0; r2 < 4; ++r2) {
                        float v = acc[a][j][r2];
                        if (MODE == 0 || kslot == 0) v += bv[r2];
                        if (MODE == 0) v = fmaxf(v, 0.f);
                        hv[r2] = (__bf16)v;
                    }
                    *(bf16x4*)&Yw[(size_t)(b0 + gm) * ND + gn] = hv;
                }
            }
        }
    }
#undef GLL
}

// ---------------- combine: out[n] = g0*(y0a+y0b) + g1*(y1a+y1b) (fp32) ----------------
__global__ void k_combine(const bf16_t* __restrict__ ybuf,   // [2][SLOTS_PAD][OUTD]
                          const int* __restrict__ slotmap,
                          const float* __restrict__ tkg,
                          float* __restrict__ out) {
    int n = blockIdx.x;
    int d = threadIdx.x * 4;
    int s0 = slotmap[2 * n], s1 = slotmap[2 * n + 1];
    float g0 = tkg[2 * n],  g1 = tkg[2 * n + 1];
    const bf16_t* y2 = ybuf + (size_t)SLOTS_PAD * OUTD;
    bf16x4 a0 = *(const bf16x4*)&ybuf[(size_t)s0 * OUTD + d];
    bf16x4 a1 = *(const bf16x4*)&y2  [(size_t)s0 * OUTD + d];
    bf16x4 c0 = *(const bf16x4*)&ybuf[(size_t)s1 * OUTD + d];
    bf16x4 c1 = *(const bf16x4*)&y2  [(size_t)s1 * OUTD + d];
    f32x4 o;
#pragma unroll
    for (int r = 0; r < 4; ++r)
        o[r] = g0 * ((float)a0[r] + (float)a1[r]) + g1 * ((float)c0[r] + (float)c1[r]);
    *(f32x4*)&out[(size_t)n * OUTD + d] = o;
}

extern "C" void kernel_launch(void* const* d_in, const int* in_sizes, int n_in,
                              void* d_out, int out_size, void* d_ws, size_t ws_size,
                              hipStream_t stream) {
    const float* x  = (const float*)d_in[0];
    const float* wg = (const float*)d_in[1];
    const float* w1 = (const float*)d_in[2];
    const float* b1 = (const float*)d_in[3];
    const float* w2 = (const float*)d_in[4];
    const float* b2 = (const float*)d_in[5];
    float* out = (float*)d_out;

    char* ws = (char*)d_ws;
    size_t o = 0;
    auto alloc = [&](size_t b) { size_t r = o; o = (o + b + 255) & ~(size_t)255; return r; };
    int*    counts  = (int*)(ws + alloc(NE * 4));
    int*    cursor  = (int*)(ws + alloc(NE * 4));
    int*    bases   = (int*)(ws + alloc(NE * 4));
    float*  imp     = (float*)(ws + alloc(NE * 4));
    int*    tki     = (int*)(ws + alloc(SLOTS * 4));
    float*  tkg     = (float*)(ws + alloc(SLOTS * 4));
    int*    tok_ids = (int*)(ws + alloc(SLOTS * 4));
    int*    slotmap = (int*)(ws + alloc(SLOTS * 4));
    bf16_t* xb      = (bf16_t*)(ws + alloc((size_t)N_TOK * DIM * 2));
    size_t  w1t_off = alloc((size_t)NE * HID * DIM * 2);
    bf16_t* w1t     = (bf16_t*)(ws + w1t_off);
    bf16_t* ybuf    = (bf16_t*)(ws + w1t_off);   // [2][SLOTS_PAD][OUTD], aliases w1t (dead after GEMM-1)
    bf16_t* w2t     = (bf16_t*)(ws + alloc((size_t)NE * OUTD * HID * 2));
    bf16_t* hbuf    = (bf16_t*)(ws + alloc((size_t)SLOTS_PAD * HID * 2));
    (void)ws_size; (void)n_in; (void)in_sizes;

    hipFuncSetAttribute((const void*)&k_gemm<0,1>, hipFuncAttributeMaxDynamicSharedMemorySize, 131072);
    hipFuncSetAttribute((const void*)&k_gemm<1,2>, hipFuncAttributeMaxDynamicSharedMemorySize, 131072);

    hipMemsetAsync(ws, 0, 1024, stream);   // counts + cursor

    k_gatecast<<<N_TOK, 64, 0, stream>>>(x, wg, xb, tki, tkg, counts);
    k_transpose<<<dim3(HID / 64, DIM / 64, NE), 256, 0, stream>>>(w1, w1t, DIM, HID);
    k_transpose<<<dim3(OUTD / 64, HID / 64, NE), 256, 0, stream>>>(w2, w2t, HID, OUTD);
    k_importance<<<NE, 256, 0, stream>>>(tki, tkg, imp);
    k_finalize<<<1, 64, 0, stream>>>(imp, counts, bases, out + (size_t)N_TOK * OUTD);
    k_build<<<SLOTS / 256, 256, 0, stream>>>(tki, bases, cursor, tok_ids, slotmap);

    // grid = NE * NP * ZB * KSPLIT, expert in low 3 bits (XCD pin)
    k_gemm<0,1><<<NE * (HID / 256) * 4, 512, 131072, stream>>>(
        xb, w1t, b1, tok_ids, bases, counts, hbuf);
    k_gemm<1,2><<<NE * (OUTD / 256) * 4 * 2, 512, 131072, stream>>>(
        hbuf, w2t, b2, tok_ids, bases, counts, ybuf);

    k_combine<<<N_TOK, 256, 0, stream>>>(ybuf, slotmap, tkg, out);
}

// Round 8
// 464.356 us; speedup vs baseline: 1.0233x; 1.0233x over previous
//
#include <hip/hip_runtime.h>
#include <hip/hip_bf16.h>
#include <stdint.h>

#define N_TOK 4096
#define DIM   1024
#define NE    8
#define HID   4096
#define OUTD  1024
#define TOPK  2
#define SLOTS (N_TOK*TOPK)
#define SLOTS_PAD (SLOTS+256)

typedef __bf16 bf16_t;
typedef __attribute__((ext_vector_type(8))) __bf16 bf16x8;
typedef __attribute__((ext_vector_type(4))) __bf16 bf16x4;
typedef __attribute__((ext_vector_type(4))) float  f32x4;

// ---------------- fused gating (fp64 logits, top-2, softmax) + x -> bf16 cast ----------------
__global__ void k_gatecast(const float* __restrict__ x, const float* __restrict__ wg,
                           bf16_t* __restrict__ xb,
                           int* __restrict__ tki, float* __restrict__ tkg,
                           int* __restrict__ counts) {
    int n = blockIdx.x;
    int lane = threadIdx.x;            // 64 threads = 1 wave
    const float* xr = x + (size_t)n * DIM;
    double acc[NE];
#pragma unroll
    for (int e = 0; e < NE; ++e) acc[e] = 0.0;
#pragma unroll
    for (int i = 0; i < 4; ++i) {
        int d0 = i * 256 + lane * 4;
        float4 v = *(const float4*)&xr[d0];
        bf16x4 o;
        o[0] = (__bf16)v.x; o[1] = (__bf16)v.y; o[2] = (__bf16)v.z; o[3] = (__bf16)v.w;
        *(bf16x4*)&xb[(size_t)n * DIM + d0] = o;
        const float* wr = wg + (size_t)d0 * NE;
#pragma unroll
        for (int j = 0; j < 4; ++j) {
            double xv = (double)((&v.x)[j]);
#pragma unroll
            for (int e = 0; e < NE; ++e) acc[e] += xv * (double)wr[j * NE + e];
        }
    }
#pragma unroll
    for (int e = 0; e < NE; ++e)
        for (int off = 32; off > 0; off >>= 1) acc[e] += __shfl_xor(acc[e], off);
    if (lane == 0) {
        int i0 = 0; double v0 = acc[0];
#pragma unroll
        for (int e = 1; e < NE; ++e) if (acc[e] > v0) { v0 = acc[e]; i0 = e; }
        int i1 = -1; double v1 = -1e300;
#pragma unroll
        for (int e = 0; e < NE; ++e) if (e != i0 && acc[e] > v1) { v1 = acc[e]; i1 = e; }
        double e1 = exp(v1 - v0);
        double s = 1.0 + e1;
        tki[n*2]   = i0;  tki[n*2+1] = i1;
        tkg[n*2]   = (float)(1.0 / s);
        tkg[n*2+1] = (float)(e1 / s);
        atomicAdd(&counts[i0], 1);
        atomicAdd(&counts[i1], 1);
    }
}

// ---------------- importance: deterministic per-expert reduction ----------------
__global__ void k_importance(const int* __restrict__ tki, const float* __restrict__ tkg,
                             float* __restrict__ imp) {
    int e = blockIdx.x, t = threadIdx.x;
    __shared__ float red[256];
    float s = 0.f;
    for (int i = t; i < SLOTS; i += 256) s += (tki[i] == e) ? tkg[i] : 0.f;
    red[t] = s; __syncthreads();
    for (int off = 128; off > 0; off >>= 1) {
        if (t < off) red[t] += red[t + off];
        __syncthreads();
    }
    if (t == 0) imp[e] = red[0];
}

// ---------------- aux loss + prefix-sum bases ----------------
__global__ void k_finalize(const float* __restrict__ imp, const int* __restrict__ counts,
                           int* __restrict__ bases, float* __restrict__ aux_out) {
    if (threadIdx.x == 0 && blockIdx.x == 0) {
        float m = 0.f;
        for (int e = 0; e < NE; ++e) m += imp[e];
        m /= (float)NE;
        float var = 0.f;
        for (int e = 0; e < NE; ++e) { float d = imp[e] - m; var += d * d; }
        var /= (float)NE;
        aux_out[0] = 0.01f * var / (m * m + 1e-10f);
        int b = 0;
        for (int e = 0; e < NE; ++e) { bases[e] = b; b += counts[e]; }
    }
}

// ---------------- build per-expert token lists + inverse slot map ----------------
__global__ void k_build(const int* __restrict__ tki,
                        const int* __restrict__ bases, int* __restrict__ cursor,
                        int* __restrict__ tok_ids, int* __restrict__ slotmap) {
    int i = blockIdx.x * 256 + threadIdx.x;
    if (i < SLOTS) {
        int e = tki[i];
        int p = atomicAdd(&cursor[e], 1);
        int s = bases[e] + p;
        tok_ids[s] = i >> 1;
        slotmap[i] = s;
    }
}

// ---------------- W [E][R][C] fp32 -> Wt [E][C][R] bf16, 64x64 tiles ----------------
// bf16x8 (16B) coalesced stores; LDS reads 2-way max (free).
__global__ void k_transpose(const float* __restrict__ src, bf16_t* __restrict__ dst,
                            int R, int C) {
    __shared__ float tile[64][65];
    const size_t slab = (size_t)R * C;
    const float* s = src + slab * blockIdx.z;
    bf16_t*      d = dst + slab * blockIdx.z;
    int c0 = blockIdx.x * 64, r0 = blockIdx.y * 64;
    int tx = threadIdx.x & 15;
    int ty = threadIdx.x >> 4;
#pragma unroll
    for (int p = 0; p < 4; ++p) {
        int rr = p * 16 + ty;
        float4 v = *(const float4*)&s[(size_t)(r0 + rr) * C + c0 + tx * 4];
        tile[rr][tx*4+0] = v.x; tile[rr][tx*4+1] = v.y;
        tile[rr][tx*4+2] = v.z; tile[rr][tx*4+3] = v.w;
    }
    __syncthreads();
    int c8 = (threadIdx.x & 7) * 8;     // 8 source rows -> 8 out cols
    int rb = threadIdx.x >> 3;          // 0..31 source col
#pragma unroll
    for (int p = 0; p < 2; ++p) {
        int cc = p * 32 + rb;           // source col = out row - c0
        bf16x8 o;
#pragma unroll
        for (int u = 0; u < 8; ++u) o[u] = (__bf16)tile[c8 + u][cc];
        *(bf16x8*)&d[(size_t)(c0 + cc) * R + r0 + c8] = o;
    }
}

// ---------------- grouped GEMM, 256x256 tile, BK=64, 8 waves, TRUE 8-phase ----------------
// 2 K-tile LDS buffers (128 KiB). Per K-tile T (buf cb=T&1), 4 phases, 1 barrier each:
//  ph0: rd fb[4][2]+fa(m0)[4][2] | stage Am1(T+1)->cb^1 | bar | lgkm0 | 16 MFMA (m0,n01)
//  ph1:                            stage Bnp0(T+1)->cb^1 | bar |        16 MFMA (m0,n23)
//  ph2: rd fa(m1)[4][2]          | stage Am0(T+2)->cb   | bar | lgkm0 | 16 MFMA (m1,n23)
//  ph3:                            stage Bnp1(T+2)->cb  | vmcnt(4) | bar | 16 MFMA (m1,n01)
// Freed-region proof: Am0(T) reads complete by ph0's lgkm0 (2 barriers before ph2's
// overwrite); fb(T) reads complete by ph0's lgkm0 (3 barriers before ph3's Bnp1 write).
// vmcnt(4) = the 2 units staged after T+1's last unit; never drains in steady state (T4).
// Swizzle = R5's verified zero-conflict layout: 64-elem rows, phys chunk = chunk ^ (row&7),
// GLL source pre-permuted ((L&7)^(L>>3))<<3, read chunk (lq^(lr&7))<<3 ^ kk<<5.
// Grid 256 = 8 XCD x 32 blocks (1/CU); flattened per-XCD tile worklist.
// MODE 0: hbuf[slot] = relu(x_gather @ W1t^T + b1)
// MODE 1 (KSPLIT=2): Y[kslot][slot] = h @ W2t^T (+b2 on kslot 0)
template <int MODE, int KSPLIT>
__global__ __launch_bounds__(512, 1)
void k_gemm(const bf16_t* __restrict__ A,    // MODE0: xb [N][DIM]; MODE1: hbuf [SLOTS_PAD][HID]
            const bf16_t* __restrict__ Bt,   // MODE0: w1t [E][HID][DIM]; MODE1: w2t [E][OUTD][HID]
            const float* __restrict__ bias,
            const int* __restrict__ tok_ids,
            const int* __restrict__ bases,
            const int* __restrict__ counts,
            bf16_t* __restrict__ Y) {
    constexpr int KD   = (MODE == 0) ? DIM : HID;
    constexpr int ND   = (MODE == 0) ? HID : OUTD;
    constexpr int NP   = ND / 256;          // 16 / 4
    constexpr int KLEN = KD / KSPLIT;       // 1024 / 2048
    constexpr int KT   = KLEN / 64;         // 16 / 32

    const int e  = blockIdx.x & 7;          // expert pinned to XCD
    const int lb = blockIdx.x >> 3;         // 0..31 local block
    const int ne = counts[e];
    if (ne == 0) return;
    const int b0 = bases[e];
    const int NT = (ne + 255) >> 8;
    const int NTILES = NP * NT * KSPLIT;

    extern __shared__ bf16_t lds[];         // lA [2][256][64] | lB [2][256][64]
    bf16_t* lB_ = lds + 32768;

    const int t = threadIdx.x, w = t >> 6, L = t & 63;
    const int wm = w >> 2, wn = w & 3;      // 2 x 4 wave grid; per-wave out 128x64
    const int lr = L & 15, lq = L >> 4;
    const int Lrow = L >> 3;                             // 0..7 within 8-row GLL group
    const int srcc = (((L & 7) ^ Lrow) << 3);            // pre-swizzled source col (elems)
    const int pc   = ((lq ^ (lr & 7)) << 3);             // swizzled read chunk base

#define GLL(srcp, dstp) __builtin_amdgcn_global_load_lds( \
        (const __attribute__((address_space(1))) uint32_t*)(srcp), \
        (__attribute__((address_space(3))) uint32_t*)(dstp), 16, 0, 0)
// stage A unit u (u=0: rows {0-63,128-191}; u=1: +64) for K-tile Tt into buffer bsl
#define SA(u, Tt, bsl) { \
        GLL(asrc[u][0] + (Tt) * 64, lds + (bsl) * 16384 + ((u) * 64 + w * 8) * 64); \
        GLL(asrc[u][1] + (Tt) * 64, lds + (bsl) * 16384 + ((u) * 64 + 128 + w * 8) * 64); }
// stage B unit v (v=0: rows ==[0,32) mod 64; v=1: +32)
#define SB(v, Tt, bsl) { \
        GLL(bsrc[v][0] + (Tt) * 64, lB_ + (bsl) * 16384 + ((w >> 1) * 64 + (v) * 32 + (w & 1) * 16) * 64); \
        GLL(bsrc[v][1] + (Tt) * 64, lB_ + (bsl) * 16384 + ((w >> 1) * 64 + (v) * 32 + (w & 1) * 16 + 8) * 64); }

    for (int ti = lb; ti < NTILES; ti += 32) {
        int panel, y, kslot;
        if (MODE == 0) { panel = ti & 15; y = ti >> 4; kslot = 0; }
        else           { int q = ti & 7; panel = q >> 1; kslot = q & 1; y = ti >> 3; }
        const int m0 = y * 256;
        const int n0 = panel * 256;
        const int koff = kslot * KLEN;
        bf16_t* __restrict__ Yw = Y + (size_t)kslot * SLOTS_PAD * ND;

        // global stage pointers
        const bf16_t* asrc[2][2];
#pragma unroll
        for (int u = 0; u < 2; ++u)
#pragma unroll
            for (int s = 0; s < 2; ++s) {
                int mm = m0 + u * 64 + s * 128 + w * 8 + Lrow;
                int rr = (mm < ne) ? mm : (ne - 1);
                if (MODE == 0) asrc[u][s] = A + (size_t)tok_ids[b0 + rr] * KD + koff + srcc;
                else           asrc[u][s] = A + (size_t)(b0 + rr) * KD + koff + srcc;
            }
        const bf16_t* bsrc[2][2];
#pragma unroll
        for (int v = 0; v < 2; ++v)
#pragma unroll
            for (int s = 0; s < 2; ++s) {
                int idx = w * 2 + s;
                int nr = n0 + (idx >> 2) * 64 + v * 32 + (idx & 3) * 8 + Lrow;
                bsrc[v][s] = Bt + ((size_t)e * ND + nr) * KD + koff + srcc;
            }

        f32x4 acc[8][4];
#pragma unroll
        for (int i = 0; i < 8; ++i)
#pragma unroll
            for (int j = 0; j < 4; ++j) acc[i][j] = (f32x4){0.f, 0.f, 0.f, 0.f};

        // prologue: T0 all 4 units -> buf0; T1 first 2 units -> buf1; wait T0 landed
        SA(0, 0, 0); SB(1, 0, 0); SA(1, 0, 0); SB(0, 0, 0);
        SA(0, 1, 1); SB(1, 1, 1);
        asm volatile("s_waitcnt vmcnt(4)" ::: "memory");
        __builtin_amdgcn_s_barrier();

#pragma unroll 2
        for (int T = 0; T < KT; ++T) {
            const int cb = T & 1;
            const bf16_t* bA = lds + cb * 16384;
            const bf16_t* bB = lB_ + cb * 16384;
            bf16x8 fb[4][2], fa[4][2];

            // ---- ph0: rd fb all + fa m0 | stage Am1(T+1) | MFMA (m0, n0-1) ----
#pragma unroll
            for (int j = 0; j < 4; ++j)
#pragma unroll
                for (int kk = 0; kk < 2; ++kk)
                    fb[j][kk] = *(const bf16x8*)(bB + (wn * 64 + j * 16 + lr) * 64 + (pc ^ (kk << 5)));
#pragma unroll
            for (int i = 0; i < 4; ++i)
#pragma unroll
                for (int kk = 0; kk < 2; ++kk)
                    fa[i][kk] = *(const bf16x8*)(bA + (wm * 128 + i * 16 + lr) * 64 + (pc ^ (kk << 5)));
            if (T + 1 < KT) SA(1, T + 1, cb ^ 1);
            __builtin_amdgcn_s_barrier();
            asm volatile("s_waitcnt lgkmcnt(0)" ::: "memory");
            __builtin_amdgcn_sched_barrier(0);
            __builtin_amdgcn_s_setprio(1);
#pragma unroll
            for (int i = 0; i < 4; ++i)
#pragma unroll
                for (int j = 0; j < 2; ++j)
#pragma unroll
                    for (int kk = 0; kk < 2; ++kk)
                        acc[i][j] = __builtin_amdgcn_mfma_f32_16x16x32_bf16(fb[j][kk], fa[i][kk], acc[i][j], 0, 0, 0);
            __builtin_amdgcn_s_setprio(0);

            // ---- ph1: stage Bnp0(T+1) | MFMA (m0, n2-3) ----
            if (T + 1 < KT) SB(0, T + 1, cb ^ 1);
            __builtin_amdgcn_s_barrier();
            __builtin_amdgcn_s_setprio(1);
#pragma unroll
            for (int i = 0; i < 4; ++i)
#pragma unroll
                for (int j = 2; j < 4; ++j)
#pragma unroll
                    for (int kk = 0; kk < 2; ++kk)
                        acc[i][j] = __builtin_amdgcn_mfma_f32_16x16x32_bf16(fb[j][kk], fa[i][kk], acc[i][j], 0, 0, 0);
            __builtin_amdgcn_s_setprio(0);

            // ---- ph2: rd fa m1 | stage Am0(T+2) | MFMA (m1, n2-3) ----
#pragma unroll
            for (int i = 0; i < 4; ++i)
#pragma unroll
                for (int kk = 0; kk < 2; ++kk)
                    fa[i][kk] = *(const bf16x8*)(bA + (wm * 128 + 64 + i * 16 + lr) * 64 + (pc ^ (kk << 5)));
            if (T + 2 < KT) SA(0, T + 2, cb);
            __builtin_amdgcn_s_barrier();
            asm volatile("s_waitcnt lgkmcnt(0)" ::: "memory");
            __builtin_amdgcn_sched_barrier(0);
            __builtin_amdgcn_s_setprio(1);
#pragma unroll
            for (int i = 0; i < 4; ++i)
#pragma unroll
                for (int j = 2; j < 4; ++j)
#pragma unroll
                    for (int kk = 0; kk < 2; ++kk)
                        acc[4 + i][j] = __builtin_amdgcn_mfma_f32_16x16x32_bf16(fb[j][kk], fa[i][kk], acc[4 + i][j], 0, 0, 0);
            __builtin_amdgcn_s_setprio(0);

            // ---- ph3: stage Bnp1(T+2) | vmcnt | MFMA (m1, n0-1) ----
            if (T + 2 < KT) SB(1, T + 2, cb);
            if (T + 1 < KT) {
                if (T + 2 < KT) asm volatile("s_waitcnt vmcnt(4)" ::: "memory");
                else            asm volatile("s_waitcnt vmcnt(0)" ::: "memory");
            }
            __builtin_amdgcn_s_barrier();
            __builtin_amdgcn_s_setprio(1);
#pragma unroll
            for (int i = 0; i < 4; ++i)
#pragma unroll
                for (int j = 0; j < 2; ++j)
#pragma unroll
                    for (int kk = 0; kk < 2; ++kk)
                        acc[4 + i][j] = __builtin_amdgcn_mfma_f32_16x16x32_bf16(fb[j][kk], fa[i][kk], acc[4 + i][j], 0, 0, 0);
            __builtin_amdgcn_s_setprio(0);
        }

        // ---------------- epilogue: bf16 store ----------------
#pragma unroll
        for (int a = 0; a < 8; ++a) {
            int ml = wm * 128 + a * 16 + lr;
            int gm = m0 + ml;
            if (gm < ne) {
#pragma unroll
                for (int j = 0; j < 4; ++j) {
                    int gn = n0 + wn * 64 + j * 16 + lq * 4;
                    bf16x4 hv;
                    f32x4 bv = *(const f32x4*)&bias[(size_t)e * ND + gn];
#pragma unroll
                    for (int r2 = 0; r2 < 4; ++r2) {
                        float v = acc[a][j][r2];
                        if (MODE == 0 || kslot == 0) v += bv[r2];
                        if (MODE == 0) v = fmaxf(v, 0.f);
                        hv[r2] = (__bf16)v;
                    }
                    *(bf16x4*)&Yw[(size_t)(b0 + gm) * ND + gn] = hv;
                }
            }
        }
    }
#undef SA
#undef SB
#undef GLL
}

// ---------------- combine: out[n] = g0*(y0a+y0b) + g1*(y1a+y1b) (fp32) ----------------
__global__ void k_combine(const bf16_t* __restrict__ ybuf,   // [2][SLOTS_PAD][OUTD]
                          const int* __restrict__ slotmap,
                          const float* __restrict__ tkg,
                          float* __restrict__ out) {
    int n = blockIdx.x;
    int d = threadIdx.x * 4;
    int s0 = slotmap[2 * n], s1 = slotmap[2 * n + 1];
    float g0 = tkg[2 * n],  g1 = tkg[2 * n + 1];
    const bf16_t* y2 = ybuf + (size_t)SLOTS_PAD * OUTD;
    bf16x4 a0 = *(const bf16x4*)&ybuf[(size_t)s0 * OUTD + d];
    bf16x4 a1 = *(const bf16x4*)&y2  [(size_t)s0 * OUTD + d];
    bf16x4 c0 = *(const bf16x4*)&ybuf[(size_t)s1 * OUTD + d];
    bf16x4 c1 = *(const bf16x4*)&y2  [(size_t)s1 * OUTD + d];
    f32x4 o;
#pragma unroll
    for (int r = 0; r < 4; ++r)
        o[r] = g0 * ((float)a0[r] + (float)a1[r]) + g1 * ((float)c0[r] + (float)c1[r]);
    *(f32x4*)&out[(size_t)n * OUTD + d] = o;
}

extern "C" void kernel_launch(void* const* d_in, const int* in_sizes, int n_in,
                              void* d_out, int out_size, void* d_ws, size_t ws_size,
                              hipStream_t stream) {
    const float* x  = (const float*)d_in[0];
    const float* wg = (const float*)d_in[1];
    const float* w1 = (const float*)d_in[2];
    const float* b1 = (const float*)d_in[3];
    const float* w2 = (const float*)d_in[4];
    const float* b2 = (const float*)d_in[5];
    float* out = (float*)d_out;

    char* ws = (char*)d_ws;
    size_t o = 0;
    auto alloc = [&](size_t b) { size_t r = o; o = (o + b + 255) & ~(size_t)255; return r; };
    int*    counts  = (int*)(ws + alloc(NE * 4));
    int*    cursor  = (int*)(ws + alloc(NE * 4));
    int*    bases   = (int*)(ws + alloc(NE * 4));
    float*  imp     = (float*)(ws + alloc(NE * 4));
    int*    tki     = (int*)(ws + alloc(SLOTS * 4));
    float*  tkg     = (float*)(ws + alloc(SLOTS * 4));
    int*    tok_ids = (int*)(ws + alloc(SLOTS * 4));
    int*    slotmap = (int*)(ws + alloc(SLOTS * 4));
    bf16_t* xb      = (bf16_t*)(ws + alloc((size_t)N_TOK * DIM * 2));
    size_t  w1t_off = alloc((size_t)NE * HID * DIM * 2);
    bf16_t* w1t     = (bf16_t*)(ws + w1t_off);
    bf16_t* ybuf    = (bf16_t*)(ws + w1t_off);   // [2][SLOTS_PAD][OUTD], aliases w1t (dead after GEMM-1)
    bf16_t* w2t     = (bf16_t*)(ws + alloc((size_t)NE * OUTD * HID * 2));
    bf16_t* hbuf    = (bf16_t*)(ws + alloc((size_t)SLOTS_PAD * HID * 2));
    (void)ws_size; (void)n_in; (void)in_sizes;

    hipFuncSetAttribute((const void*)&k_gemm<0,1>, hipFuncAttributeMaxDynamicSharedMemorySize, 131072);
    hipFuncSetAttribute((const void*)&k_gemm<1,2>, hipFuncAttributeMaxDynamicSharedMemorySize, 131072);

    hipMemsetAsync(ws, 0, 1024, stream);   // counts + cursor

    k_gatecast<<<N_TOK, 64, 0, stream>>>(x, wg, xb, tki, tkg, counts);
    k_transpose<<<dim3(HID / 64, DIM / 64, NE), 256, 0, stream>>>(w1, w1t, DIM, HID);
    k_transpose<<<dim3(OUTD / 64, HID / 64, NE), 256, 0, stream>>>(w2, w2t, HID, OUTD);
    k_importance<<<NE, 256, 0, stream>>>(tki, tkg, imp);
    k_finalize<<<1, 64, 0, stream>>>(imp, counts, bases, out + (size_t)N_TOK * OUTD);
    k_build<<<SLOTS / 256, 256, 0, stream>>>(tki, bases, cursor, tok_ids, slotmap);

    // 256 blocks = 8 XCD x 32 (1/CU); per-XCD flattened tile worklist
    k_gemm<0,1><<<256, 512, 131072, stream>>>(xb, w1t, b1, tok_ids, bases, counts, hbuf);
    k_gemm<1,2><<<256, 512, 131072, stream>>>(hbuf, w2t, b2, tok_ids, bases, counts, ybuf);

    k_combine<<<N_TOK, 256, 0, stream>>>(ybuf, slotmap, tkg, out);
}

// Round 9
// 442.716 us; speedup vs baseline: 1.0733x; 1.0489x over previous
//
#include <hip/hip_runtime.h>
#include <hip/hip_bf16.h>
#include <stdint.h>

#define N_TOK 4096
#define DIM   1024
#define NE    8
#define HID   4096
#define OUTD  1024
#define TOPK  2
#define SLOTS (N_TOK*TOPK)

typedef __bf16 bf16_t;
typedef __attribute__((ext_vector_type(8))) __bf16 bf16x8;
typedef __attribute__((ext_vector_type(4))) __bf16 bf16x4;
typedef __attribute__((ext_vector_type(4))) float  f32x4;

// ---------------- fused gating (fp64 logits, top-2, softmax) + x -> bf16 cast ----------------
__global__ void k_gatecast(const float* __restrict__ x, const float* __restrict__ wg,
                           bf16_t* __restrict__ xb,
                           int* __restrict__ tki, float* __restrict__ tkg,
                           int* __restrict__ counts) {
    int n = blockIdx.x;
    int lane = threadIdx.x;            // 64 threads = 1 wave
    const float* xr = x + (size_t)n * DIM;
    double acc[NE];
#pragma unroll
    for (int e = 0; e < NE; ++e) acc[e] = 0.0;
#pragma unroll
    for (int i = 0; i < 4; ++i) {
        int d0 = i * 256 + lane * 4;
        float4 v = *(const float4*)&xr[d0];
        bf16x4 o;
        o[0] = (__bf16)v.x; o[1] = (__bf16)v.y; o[2] = (__bf16)v.z; o[3] = (__bf16)v.w;
        *(bf16x4*)&xb[(size_t)n * DIM + d0] = o;
        const float* wr = wg + (size_t)d0 * NE;
#pragma unroll
        for (int j = 0; j < 4; ++j) {
            double xv = (double)((&v.x)[j]);
#pragma unroll
            for (int e = 0; e < NE; ++e) acc[e] += xv * (double)wr[j * NE + e];
        }
    }
#pragma unroll
    for (int e = 0; e < NE; ++e)
        for (int off = 32; off > 0; off >>= 1) acc[e] += __shfl_xor(acc[e], off);
    if (lane == 0) {
        int i0 = 0; double v0 = acc[0];
#pragma unroll
        for (int e = 1; e < NE; ++e) if (acc[e] > v0) { v0 = acc[e]; i0 = e; }
        int i1 = -1; double v1 = -1e300;
#pragma unroll
        for (int e = 0; e < NE; ++e) if (e != i0 && acc[e] > v1) { v1 = acc[e]; i1 = e; }
        double e1 = exp(v1 - v0);
        double s = 1.0 + e1;
        tki[n*2]   = i0;  tki[n*2+1] = i1;
        tkg[n*2]   = (float)(1.0 / s);
        tkg[n*2+1] = (float)(e1 / s);
        atomicAdd(&counts[i0], 1);
        atomicAdd(&counts[i1], 1);
    }
}

// ---------------- importance: deterministic per-expert reduction ----------------
__global__ void k_importance(const int* __restrict__ tki, const float* __restrict__ tkg,
                             float* __restrict__ imp) {
    int e = blockIdx.x, t = threadIdx.x;
    __shared__ float red[256];
    float s = 0.f;
    for (int i = t; i < SLOTS; i += 256) s += (tki[i] == e) ? tkg[i] : 0.f;
    red[t] = s; __syncthreads();
    for (int off = 128; off > 0; off >>= 1) {
        if (t < off) red[t] += red[t + off];
        __syncthreads();
    }
    if (t == 0) imp[e] = red[0];
}

// ---------------- aux loss + prefix-sum bases ----------------
__global__ void k_finalize(const float* __restrict__ imp, const int* __restrict__ counts,
                           int* __restrict__ bases, float* __restrict__ aux_out) {
    if (threadIdx.x == 0 && blockIdx.x == 0) {
        float m = 0.f;
        for (int e = 0; e < NE; ++e) m += imp[e];
        m /= (float)NE;
        float var = 0.f;
        for (int e = 0; e < NE; ++e) { float d = imp[e] - m; var += d * d; }
        var /= (float)NE;
        aux_out[0] = 0.01f * var / (m * m + 1e-10f);
        int b = 0;
        for (int e = 0; e < NE; ++e) { bases[e] = b; b += counts[e]; }
    }
}

// ---------------- build per-expert token lists + inverse slot map ----------------
__global__ void k_build(const int* __restrict__ tki,
                        const int* __restrict__ bases, int* __restrict__ cursor,
                        int* __restrict__ tok_ids, int* __restrict__ slotmap) {
    int i = blockIdx.x * 256 + threadIdx.x;
    if (i < SLOTS) {
        int e = tki[i];
        int p = atomicAdd(&cursor[e], 1);
        int s = bases[e] + p;
        tok_ids[s] = i >> 1;
        slotmap[i] = s;
    }
}

// ---------------- W [E][R][C] fp32 -> Wt [E][C][R] bf16, 64x64 tiles ----------------
__global__ void k_transpose(const float* __restrict__ src, bf16_t* __restrict__ dst,
                            int R, int C) {
    __shared__ float tile[64][65];
    const size_t slab = (size_t)R * C;
    const float* s = src + slab * blockIdx.z;
    bf16_t*      d = dst + slab * blockIdx.z;
    int c0 = blockIdx.x * 64, r0 = blockIdx.y * 64;
    int tx = threadIdx.x & 15;
    int ty = threadIdx.x >> 4;
#pragma unroll
    for (int p = 0; p < 4; ++p) {
        int rr = p * 16 + ty;
        float4 v = *(const float4*)&s[(size_t)(r0 + rr) * C + c0 + tx * 4];
        tile[rr][tx*4+0] = v.x; tile[rr][tx*4+1] = v.y;
        tile[rr][tx*4+2] = v.z; tile[rr][tx*4+3] = v.w;
    }
    __syncthreads();
    int c8 = (threadIdx.x & 7) * 8;
    int rb = threadIdx.x >> 3;
#pragma unroll
    for (int p = 0; p < 2; ++p) {
        int cc = p * 32 + rb;
        bf16x8 o;
#pragma unroll
        for (int u = 0; u < 8; ++u) o[u] = (__bf16)tile[c8 + u][cc];
        *(bf16x8*)&d[(size_t)(c0 + cc) * R + r0 + c8] = o;
    }
}

// ---------------- grouped GEMM, 128x256 tile, BK=64, 8 waves, read-ahead pipeline ----------------
// 3 LDS buffers (A 3x[128][64] + B 3x[256][64] = 144 KiB). Per sub-iter C (1 barrier):
//   vmcnt(6)  [tile C+1 landed, C+2 stays in flight - counted, T4]
//   lgkm0     [reads(C) done - they overlapped MFMA(C-1)]
//   s_barrier
//   stage tile C+3 -> buf[C%3]  (reads(C) confirmed by ALL waves pre-barrier -> dead region)
//   issue reads(C+1) -> alternate register set
//   MFMA(C) from current set  (ds_read completion hides under this window)
// Both GEMMs have KLEN=1024 (MODE1 via KSPLIT=4), KT=16. Swizzle = verified zero-conflict
// layout (R5/R8): srcc=((L&7)^(L>>3))<<3, read chunk (lq^(lr&7))<<3 ^ kk<<5, both-sides.
// MODE 0: hbuf[slot] = relu(x_gather @ W1t^T + b1)
// MODE 1: ybuf[kslot][slot] = h @ W2t^T (+b2 on kslot 0), 4 partials combined later.
template <int MODE>
__global__ __launch_bounds__(512, 1)
void k_gemm(const bf16_t* __restrict__ A,    // MODE0: xb [N][DIM]; MODE1: hbuf [SLOTS][HID]
            const bf16_t* __restrict__ Bt,   // MODE0: w1t [E][HID][DIM]; MODE1: w2t [E][OUTD][HID]
            const float* __restrict__ bias,
            const int* __restrict__ tok_ids,
            const int* __restrict__ bases,
            const int* __restrict__ counts,
            bf16_t* __restrict__ Y) {
    constexpr int KD = (MODE == 0) ? DIM : HID;   // A/B row stride
    constexpr int ND = (MODE == 0) ? HID : OUTD;
    constexpr int KT = 16;                        // KLEN = 1024 both modes

    const int e  = blockIdx.x & 7;                // expert pinned to XCD
    const int lb = blockIdx.x >> 3;               // 0..31
    const int ne = counts[e];
    const int b0 = bases[e];
    const int NTy = (ne + 127) >> 7;
    const int NTILES = 16 * NTy;                  // MODE0: 16 panels; MODE1: 4 panels x 4 kslots

    extern __shared__ bf16_t lds[];               // A: 3*8192 elems @0 ; B: 3*16384 @24576

    const int t = threadIdx.x, w = t >> 6, L = t & 63;
    const int wm = w >> 2, wn = w & 3;            // 2M x 4N waves; per-wave out 64x64
    const int lr = L & 15, lq = L >> 4;
    const int Lrow = L >> 3;
    const int srcc = (((L & 7) ^ Lrow) << 3);     // pre-swizzled source col (elems)
    const int pc   = ((lq ^ (lr & 7)) << 3);      // swizzled read chunk base

#define GLL(srcp, dste) __builtin_amdgcn_global_load_lds( \
        (const __attribute__((address_space(1))) uint32_t*)(srcp), \
        (__attribute__((address_space(3))) uint32_t*)(lds + (dste)), 16, 0, 0)
#define STAGE(Tt, bsl) { \
        GLL(aptr[0] + (Tt) * 64, (bsl) * 8192 + (w * 16 + 0) * 64); \
        GLL(aptr[1] + (Tt) * 64, (bsl) * 8192 + (w * 16 + 8) * 64); \
        GLL(bptr[0] + (Tt) * 64, 24576 + (bsl) * 16384 + (w * 32 + 0) * 64); \
        GLL(bptr[1] + (Tt) * 64, 24576 + (bsl) * 16384 + (w * 32 + 8) * 64); \
        GLL(bptr[2] + (Tt) * 64, 24576 + (bsl) * 16384 + (w * 32 + 16) * 64); \
        GLL(bptr[3] + (Tt) * 64, 24576 + (bsl) * 16384 + (w * 32 + 24) * 64); }
#define RD(FA, FB, bsl) { \
        _Pragma("unroll") for (int i_ = 0; i_ < 4; ++i_) \
        _Pragma("unroll") for (int k_ = 0; k_ < 2; ++k_) \
            FA[i_][k_] = *(const bf16x8*)(lds + (bsl) * 8192 + (wm * 64 + i_ * 16 + lr) * 64 + (pc ^ (k_ << 5))); \
        _Pragma("unroll") for (int j_ = 0; j_ < 4; ++j_) \
        _Pragma("unroll") for (int k_ = 0; k_ < 2; ++k_) \
            FB[j_][k_] = *(const bf16x8*)(lds + 24576 + (bsl) * 16384 + (wn * 64 + j_ * 16 + lr) * 64 + (pc ^ (k_ << 5))); }
#define MM(FA, FB) { \
        __builtin_amdgcn_s_setprio(1); \
        _Pragma("unroll") for (int i_ = 0; i_ < 4; ++i_) \
        _Pragma("unroll") for (int j_ = 0; j_ < 4; ++j_) \
        _Pragma("unroll") for (int k_ = 0; k_ < 2; ++k_) \
            acc[i_][j_] = __builtin_amdgcn_mfma_f32_16x16x32_bf16(FB[j_][k_], FA[i_][k_], acc[i_][j_], 0, 0, 0); \
        __builtin_amdgcn_s_setprio(0); }
#define SUB(C, FcA, FcB, FnA, FnB) { \
        if ((C) + 2 < KT) { asm volatile("s_waitcnt vmcnt(6)" ::: "memory"); } \
        else              { asm volatile("s_waitcnt vmcnt(0)" ::: "memory"); } \
        asm volatile("s_waitcnt lgkmcnt(0)" ::: "memory"); \
        __builtin_amdgcn_sched_barrier(0); \
        __builtin_amdgcn_s_barrier(); \
        if ((C) + 3 < KT) STAGE((C) + 3, ((C) + 3) % 3); \
        if ((C) + 1 < KT) RD(FnA, FnB, ((C) + 1) % 3); \
        __builtin_amdgcn_sched_barrier(0); \
        MM(FcA, FcB); }

    for (int ti = lb; ti < NTILES; ti += 32) {
        int panel, y, kslot;
        if (MODE == 0) { panel = ti / NTy; y = ti - panel * NTy; kslot = 0; }
        else { int u = ti / NTy; y = ti - u * NTy; kslot = u >> 2; panel = u & 3; }
        const int m0 = y * 128;
        const int n0 = panel * 256;
        const int koff = (MODE == 0) ? 0 : kslot * 1024;
        bf16_t* __restrict__ Yw = (MODE == 0) ? Y : (Y + (size_t)kslot * SLOTS * OUTD);

        const bf16_t* aptr[2];
#pragma unroll
        for (int g = 0; g < 2; ++g) {
            int mm = m0 + w * 16 + g * 8 + Lrow;
            int rr = (mm < ne) ? mm : (ne - 1);
            if (MODE == 0) aptr[g] = A + (size_t)tok_ids[b0 + rr] * KD + koff + srcc;
            else           aptr[g] = A + (size_t)(b0 + rr) * KD + koff + srcc;
        }
        const bf16_t* bptr[4];
#pragma unroll
        for (int g = 0; g < 4; ++g)
            bptr[g] = Bt + ((size_t)e * ND + n0 + w * 32 + g * 8 + Lrow) * KD + koff + srcc;

        f32x4 acc[4][4];
#pragma unroll
        for (int i = 0; i < 4; ++i)
#pragma unroll
            for (int j = 0; j < 4; ++j) acc[i][j] = (f32x4){0.f, 0.f, 0.f, 0.f};

        bf16x8 fA0[4][2], fB0[4][2], fA1[4][2], fB1[4][2];

        // prologue: stage tiles 0,1,2 (18 GLL); wait tile 0; read tile 0 -> set0
        STAGE(0, 0); STAGE(1, 1); STAGE(2, 2);
        asm volatile("s_waitcnt vmcnt(12)" ::: "memory");
        __builtin_amdgcn_s_barrier();
        RD(fA0, fB0, 0);

#pragma unroll
        for (int c = 0; c < KT; c += 2) {
            SUB(c,     fA0, fB0, fA1, fB1);
            SUB(c + 1, fA1, fB1, fA0, fB0);
        }

        // ---------------- epilogue: bf16 store ----------------
        const int kbias = (MODE == 0) ? 1 : (kslot == 0 ? 1 : 0);
#pragma unroll
        for (int i = 0; i < 4; ++i) {
            int gm = m0 + wm * 64 + i * 16 + lr;
            if (gm < ne) {
#pragma unroll
                for (int j = 0; j < 4; ++j) {
                    int gn = n0 + wn * 64 + j * 16 + lq * 4;
                    f32x4 bv = *(const f32x4*)&bias[(size_t)e * ND + gn];
                    bf16x4 hv;
#pragma unroll
                    for (int r = 0; r < 4; ++r) {
                        float v = acc[i][j][r];
                        if (kbias) v += bv[r];
                        if (MODE == 0) v = fmaxf(v, 0.f);
                        hv[r] = (__bf16)v;
                    }
                    *(bf16x4*)&Yw[(size_t)(b0 + gm) * ND + gn] = hv;
                }
            }
        }
    }
#undef SUB
#undef MM
#undef RD
#undef STAGE
#undef GLL
}

// ---------------- combine: out[n] = g0*sum_s y[s][slot0] + g1*sum_s y[s][slot1] ----------------
__global__ void k_combine(const bf16_t* __restrict__ ybuf,   // [4][SLOTS][OUTD]
                          const int* __restrict__ slotmap,
                          const float* __restrict__ tkg,
                          float* __restrict__ out) {
    int n = blockIdx.x;
    int d = threadIdx.x * 4;
    int s0 = slotmap[2 * n], s1 = slotmap[2 * n + 1];
    float g0 = tkg[2 * n],  g1 = tkg[2 * n + 1];
    f32x4 o = (f32x4){0.f, 0.f, 0.f, 0.f};
#pragma unroll
    for (int s = 0; s < 4; ++s) {
        const bf16_t* ys = ybuf + (size_t)s * SLOTS * OUTD;
        bf16x4 u = *(const bf16x4*)&ys[(size_t)s0 * OUTD + d];
        bf16x4 v = *(const bf16x4*)&ys[(size_t)s1 * OUTD + d];
#pragma unroll
        for (int r = 0; r < 4; ++r)
            o[r] += g0 * (float)u[r] + g1 * (float)v[r];
    }
    *(f32x4*)&out[(size_t)n * OUTD + d] = o;
}

extern "C" void kernel_launch(void* const* d_in, const int* in_sizes, int n_in,
                              void* d_out, int out_size, void* d_ws, size_t ws_size,
                              hipStream_t stream) {
    const float* x  = (const float*)d_in[0];
    const float* wg = (const float*)d_in[1];
    const float* w1 = (const float*)d_in[2];
    const float* b1 = (const float*)d_in[3];
    const float* w2 = (const float*)d_in[4];
    const float* b2 = (const float*)d_in[5];
    float* out = (float*)d_out;

    char* ws = (char*)d_ws;
    size_t o = 0;
    auto alloc = [&](size_t b) { size_t r = o; o = (o + b + 255) & ~(size_t)255; return r; };
    int*    counts  = (int*)(ws + alloc(NE * 4));
    int*    cursor  = (int*)(ws + alloc(NE * 4));
    int*    bases   = (int*)(ws + alloc(NE * 4));
    float*  imp     = (float*)(ws + alloc(NE * 4));
    int*    tki     = (int*)(ws + alloc(SLOTS * 4));
    float*  tkg     = (float*)(ws + alloc(SLOTS * 4));
    int*    tok_ids = (int*)(ws + alloc(SLOTS * 4));
    int*    slotmap = (int*)(ws + alloc(SLOTS * 4));
    bf16_t* xb      = (bf16_t*)(ws + alloc((size_t)N_TOK * DIM * 2));
    size_t  w1t_off = alloc((size_t)NE * HID * DIM * 2);
    bf16_t* w1t     = (bf16_t*)(ws + w1t_off);
    bf16_t* ybuf    = (bf16_t*)(ws + w1t_off);   // [4][SLOTS][OUTD] = 67.1 MB = exactly w1t (dead after GEMM-1)
    bf16_t* w2t     = (bf16_t*)(ws + alloc((size_t)NE * OUTD * HID * 2));
    bf16_t* hbuf    = (bf16_t*)(ws + alloc((size_t)SLOTS * HID * 2));
    (void)ws_size; (void)n_in; (void)in_sizes;

    hipFuncSetAttribute((const void*)&k_gemm<0>, hipFuncAttributeMaxDynamicSharedMemorySize, 147456);
    hipFuncSetAttribute((const void*)&k_gemm<1>, hipFuncAttributeMaxDynamicSharedMemorySize, 147456);

    hipMemsetAsync(ws, 0, 1024, stream);   // counts + cursor

    k_gatecast<<<N_TOK, 64, 0, stream>>>(x, wg, xb, tki, tkg, counts);
    k_transpose<<<dim3(HID / 64, DIM / 64, NE), 256, 0, stream>>>(w1, w1t, DIM, HID);
    k_transpose<<<dim3(OUTD / 64, HID / 64, NE), 256, 0, stream>>>(w2, w2t, HID, OUTD);
    k_importance<<<NE, 256, 0, stream>>>(tki, tkg, imp);
    k_finalize<<<1, 64, 0, stream>>>(imp, counts, bases, out + (size_t)N_TOK * OUTD);
    k_build<<<SLOTS / 256, 256, 0, stream>>>(tki, bases, cursor, tok_ids, slotmap);

    // 256 blocks = 8 XCD x 32 (1/CU); per-XCD flattened 128x256 tile worklist
    k_gemm<0><<<256, 512, 147456, stream>>>(xb, w1t, b1, tok_ids, bases, counts, hbuf);
    k_gemm<1><<<256, 512, 147456, stream>>>(hbuf, w2t, b2, tok_ids, bases, counts, ybuf);

    k_combine<<<N_TOK, 256, 0, stream>>>(ybuf, slotmap, tkg, out);
}